// Round 4
// baseline (307.873 us; speedup 1.0000x reference)
//
#include <hip/hip_runtime.h>

#define NN 65536
#define BB 64
#define HH 1024
#define MM 64
#define RR 4

__device__ __forceinline__ float waveReduceSum(float v) {
#pragma unroll
  for (int off = 32; off > 0; off >>= 1) v += __shfl_xor(v, off, 64);
  return v;
}

__device__ __forceinline__ float fastPow(float wt, float p) {
  return __expf(p * __logf(wt));
}

// ---------------------------------------------------------------------------
// K1a: partial dots for the three 1024x64 GEMMs. grid (12, 64), block 256.
// ---------------------------------------------------------------------------
__global__ __launch_bounds__(256) void prep1_kernel(
    const float* __restrict__ h_t,
    const float* __restrict__ key_w, const float* __restrict__ erase_w,
    const float* __restrict__ add_w,
    float* __restrict__ prep_part,
    float* __restrict__ RS0p, float* __restrict__ RS1p, float* __restrict__ GSp)
{
  const int b = blockIdx.y;
  const int mat = blockIdx.x >> 2, chunk = blockIdx.x & 3;
  const int t = threadIdx.x;
  if (mat == 0 && chunk == 0) { RS0p[b * 256 + t] = 0.f; RS1p[b * 256 + t] = 0.f; }
  if (mat == 0 && chunk == 1 && b < 20) GSp[b * 256 + t] = 0.f;

  const float* Wm = (mat == 0) ? key_w : ((mat == 1) ? erase_w : add_w);
  const int c = t & 63, q = t >> 6;
  const int h0 = chunk * 256 + q * 64;
  float d = 0.f;
#pragma unroll 8
  for (int i = 0; i < 64; i++)
    d += h_t[b * HH + h0 + i] * Wm[(h0 + i) * 64 + c];
  __shared__ float red[64][5];
  red[c][q] = d;
  __syncthreads();
  if (t < 64)
    prep_part[((b * 3 + mat) * 4 + chunk) * 64 + t] =
        red[t][0] + red[t][1] + red[t][2] + red[t][3];
}

// ---------------------------------------------------------------------------
// K1b: reduce partials + activations + small dots + kn. grid 64, block 256.
// ---------------------------------------------------------------------------
__global__ __launch_bounds__(256) void prep2_kernel(
    const float* __restrict__ h_t, const float* __restrict__ prep_part,
    const float* __restrict__ key_b,
    const float* __restrict__ beta_w, const float* __restrict__ beta_b,
    const float* __restrict__ gate_w, const float* __restrict__ gate_b,
    const float* __restrict__ shift_w, const float* __restrict__ shift_b,
    const float* __restrict__ gamma_w, const float* __restrict__ gamma_b,
    const float* __restrict__ erase_b, const float* __restrict__ add_b,
    float* __restrict__ kn, float* __restrict__ e_v, float* __restrict__ a_v,
    float* __restrict__ g, float* __restrict__ gamma_,
    float* __restrict__ s, float* __restrict__ betaGlob)
{
  const int b = blockIdx.x;
  const int t = threadIdx.x;
  __shared__ float k_sh[64];
  if (t < 192) {
    const int mat = t >> 6, c = t & 63;
    const float* pp = prep_part + ((b * 3 + mat) * 4) * 64 + c;
    const float v = pp[0] + pp[64] + pp[128] + pp[192];
    if (mat == 0) k_sh[c] = fminf(fmaxf(v + key_b[c], 0.f), 1.f);
    else if (mat == 1) e_v[b * 64 + c] = fminf(fmaxf(v + erase_b[c], 0.f), 1.f);
    else a_v[b * 64 + c] = fminf(fmaxf(v + add_b[c], 0.f), 1.f);
  } else {
    const int lane = t - 192;
    float o0 = 0.f, o1 = 0.f, o2 = 0.f, o3 = 0.f, o4 = 0.f, o5 = 0.f;
#pragma unroll 4
    for (int k = 0; k < 16; k++) {
      const int hh = lane + k * 64;
      const float hv = h_t[b * HH + hh];
      o0 += hv * beta_w[hh];
      o1 += hv * gate_w[hh];
      o2 += hv * gamma_w[hh];
      o3 += hv * shift_w[hh * 3 + 0];
      o4 += hv * shift_w[hh * 3 + 1];
      o5 += hv * shift_w[hh * 3 + 2];
    }
    o0 = waveReduceSum(o0); o1 = waveReduceSum(o1); o2 = waveReduceSum(o2);
    o3 = waveReduceSum(o3); o4 = waveReduceSum(o4); o5 = waveReduceSum(o5);
    if (lane == 0) {
      betaGlob[b] = fmaxf(o0 + beta_b[0], 0.f);
      g[b]        = fminf(fmaxf(o1 + gate_b[0], 0.f), 1.f);
      gamma_[b]   = 1.0f + fmaxf(o2 + gamma_b[0], 0.f);
      const float l0 = o3 + shift_b[0], l1 = o4 + shift_b[1], l2 = o5 + shift_b[2];
      const float mx = fmaxf(l0, fmaxf(l1, l2));
      const float e0 = __expf(l0 - mx), e1 = __expf(l1 - mx), e2 = __expf(l2 - mx);
      const float inv = 1.f / (e0 + e1 + e2);
      s[b * 3 + 0] = e0 * inv; s[b * 3 + 1] = e1 * inv; s[b * 3 + 2] = e2 * inv;
    }
  }
  __syncthreads();
  if (t < 64) {
    float ss = 0.f;
    for (int j = 0; j < 64; j++) ss += k_sh[j] * k_sh[j];
    kn[b * 64 + t] = k_sh[t] / (sqrtf(ss) + 1e-8f);
  }
}

// ---------------------------------------------------------------------------
// K2 / K5: content addressing. grid 1024 (n-chunks of 64), block 256.
// Thread = one n; wave bq owns b range [bq*16, bq*16+16). Memory row held
// resident in 64 VGPRs (launch_bounds(256,4) -> 128 VGPR cap); kn/beta via
// wave-uniform scalar loads -> SGPR-operand FMAs, no vector loads in loop.
// ---------------------------------------------------------------------------
__global__ __launch_bounds__(256, 4) void content_kernel(
    const float* __restrict__ mem, const int* __restrict__ bank,
    const float* __restrict__ kn, const float* __restrict__ beta,
    float* __restrict__ E, float* __restrict__ RSp)
{
  const float* Mrow = mem + (bank ? ((size_t)(*bank) * (size_t)NN * MM) : (size_t)0);
  const int t = threadIdx.x;
  const int lane = t & 63;
  const int n = blockIdx.x * 64 + lane;
  const int bq = t >> 6;  // wave id -> b group

  float4 row[16];
  const float4* rp = (const float4*)(Mrow + (size_t)n * MM);
#pragma unroll
  for (int q = 0; q < 16; q++) row[q] = rp[q];
  float s0 = 0.f, s1 = 0.f, s2 = 0.f, s3 = 0.f;
#pragma unroll
  for (int q = 0; q < 16; q++) {
    s0 += row[q].x * row[q].x; s1 += row[q].y * row[q].y;
    s2 += row[q].z * row[q].z; s3 += row[q].w * row[q].w;
  }
  const float rinv = 1.0f / (sqrtf((s0 + s1) + (s2 + s3)) + 1e-8f);

#pragma unroll 2
  for (int i = 0; i < 16; i++) {
    const int rb = __builtin_amdgcn_readfirstlane(bq * 16 + i);
    const float4* kp = (const float4*)(kn + rb * 64);
    float d0 = 0.f, d1 = 0.f, d2 = 0.f, d3 = 0.f;
#pragma unroll
    for (int q = 0; q < 16; q++) {
      const float4 kq = kp[q];
      d0 += kq.x * row[q].x; d1 += kq.y * row[q].y;
      d2 += kq.z * row[q].z; d3 += kq.w * row[q].w;
    }
    const float e = __expf(beta[rb] * ((d0 + d1) + (d2 + d3)) * rinv);
    E[(size_t)rb * NN + n] = e;
    const float r = waveReduceSum(e);
    if (lane == 0)
      atomicAdd(&RSp[rb * 256 + (blockIdx.x & 15) * 16], r);
  }
}

// ---------------------------------------------------------------------------
// K3: vectorized streaming w_pow for NR heads sharing one E.
// grid (64 n-chunks of 1024, 64 b), block 256. float4 per thread.
// (Used only for the write head, NR=1.)
// ---------------------------------------------------------------------------
template <int NR>
__global__ __launch_bounds__(256) void wpow_all_kernel(
    const float* __restrict__ E, const float* __restrict__ wprev,
    const float* __restrict__ RSp, const float* __restrict__ g,
    const float* __restrict__ gamma_, const float* __restrict__ s,
    float* __restrict__ Wout, float* __restrict__ GSp, int slot0)
{
  const int b = blockIdx.y;
  const float gb = g[b], gmb = gamma_[b];
  const float s0 = s[b * 3], s1 = s[b * 3 + 1], s2 = s[b * 3 + 2];
  float rs = 0.f;
#pragma unroll
  for (int j = 0; j < 16; j++) rs += RSp[b * 256 + j * 16];
  const float grinv = gb / rs;
  const float omg = 1.f - gb;

  const int t = threadIdx.x, lane = t & 63, w = t >> 6;
  const int n4 = blockIdx.x * 1024 + 4 * t;  // covers n4..n4+3; lane-adjacent

  const float* Eb = E + (size_t)b * NN;
  const float4 ev = *((const float4*)(Eb + n4));
  const float gex = grinv * ev.x, gey = grinv * ev.y;
  const float gez = grinv * ev.z, gew = grinv * ev.w;
  float geL = 0.f, geR = 0.f;
  if (lane == 0 && n4 > 0) geL = grinv * Eb[n4 - 1];
  if (lane == 63 && n4 + 4 < NN) geR = grinv * Eb[n4 + 4];

  float gs_local[NR];
#pragma unroll
  for (int j = 0; j < NR; j++) gs_local[j] = 0.f;

#pragma unroll
  for (int j = 0; j < NR; j++) {
    const float* wb = wprev + ((size_t)j * BB + b) * NN;
    const float4 wv = *((const float4*)(wb + n4));
    float4 wgc;
    wgc.x = gex + omg * wv.x;
    wgc.y = gey + omg * wv.y;
    wgc.z = gez + omg * wv.z;
    wgc.w = gew + omg * wv.w;
    float up = __shfl_up(wgc.w, 1, 64);
    float dn = __shfl_down(wgc.x, 1, 64);
    if (lane == 0)  up = (n4 > 0)       ? (geL + omg * wb[n4 - 1]) : 0.f;
    if (lane == 63) dn = (n4 + 4 < NN)  ? (geR + omg * wb[n4 + 4]) : 0.f;
    float4 wt;
    wt.x = s0 * up    + s1 * wgc.x + s2 * wgc.y;
    wt.y = s0 * wgc.x + s1 * wgc.y + s2 * wgc.z;
    wt.z = s0 * wgc.y + s1 * wgc.z + s2 * wgc.w;
    wt.w = s0 * wgc.z + s1 * wgc.w + s2 * dn;
    float4 wp;
    wp.x = fastPow(wt.x, gmb); wp.y = fastPow(wt.y, gmb);
    wp.z = fastPow(wt.z, gmb); wp.w = fastPow(wt.w, gmb);
    *((float4*)(Wout + ((size_t)j * BB + b) * NN + n4)) = wp;
    gs_local[j] += wp.x + wp.y + wp.z + wp.w;
  }

  __shared__ float wsum[4][NR];
#pragma unroll
  for (int j = 0; j < NR; j++) {
    const float v = waveReduceSum(gs_local[j]);
    if (lane == 0) wsum[w][j] = v;
  }
  __syncthreads();
  if (t < NR)
    atomicAdd(&GSp[(slot0 + t) * 1024 + b * 16],
              wsum[0][t] + wsum[1][t] + wsum[2][t] + wsum[3][t]);
}

// ---------------------------------------------------------------------------
// K4: apply write head. grid 1024 (64-n), block 256.
// ---------------------------------------------------------------------------
__global__ __launch_bounds__(256) void apply_write_kernel(
    const float* __restrict__ W0, const float* __restrict__ GSp,
    const float* __restrict__ e_v, const float* __restrict__ a_v,
    const float* __restrict__ memory, const int* __restrict__ bank,
    float* __restrict__ m1)
{
  __shared__ float cw[64 * 68];
  __shared__ float e_sh[4096];
  __shared__ float a_sh[4096];
  const int t = threadIdx.x;
  const int n0 = blockIdx.x * 64;
  float gs = 0.f;
#pragma unroll
  for (int j = 0; j < 64; j++) gs += GSp[j * 16];
  const float invGS = 1.0f / (gs + 1e-5f);
#pragma unroll
  for (int q = 0; q < 4; q++) {
    ((float4*)e_sh)[t + 256 * q] = ((const float4*)e_v)[t + 256 * q];
    ((float4*)a_sh)[t + 256 * q] = ((const float4*)a_v)[t + 256 * q];
  }
#pragma unroll
  for (int rep = 0; rep < 4; rep++) {
    const int idx = rep * 256 + t;
    const int b = idx >> 4, nc = idx & 15;
    float4 v = *((const float4*)(W0 + (size_t)b * NN + n0 + nc * 4));
    v.x *= invGS; v.y *= invGS; v.z *= invGS; v.w *= invGS;
    *((float4*)&cw[b * 68 + nc * 4]) = v;
  }
  __syncthreads();
  const int nl = t >> 2, mq = t & 3;
  const int n = n0 + nl;
  float er[16], ad[16];
#pragma unroll
  for (int j = 0; j < 16; j++) { er[j] = 0.f; ad[j] = 0.f; }
  for (int b = 0; b < 64; b++) {
    const float c = cw[b * 68 + nl];
#pragma unroll
    for (int j = 0; j < 4; j++) {
      const float4 ev = *((const float4*)&e_sh[b * 64 + mq * 16 + j * 4]);
      const float4 av = *((const float4*)&a_sh[b * 64 + mq * 16 + j * 4]);
      er[j * 4 + 0] += c * ev.x; er[j * 4 + 1] += c * ev.y;
      er[j * 4 + 2] += c * ev.z; er[j * 4 + 3] += c * ev.w;
      ad[j * 4 + 0] += c * av.x; ad[j * 4 + 1] += c * av.y;
      ad[j * 4 + 2] += c * av.z; ad[j * 4 + 3] += c * av.w;
    }
  }
  const float* M0 = memory + (size_t)(*bank) * (size_t)NN * MM;
  const float4* m0p = (const float4*)(M0 + (size_t)n * MM + mq * 16);
  float4* m1p = (float4*)(m1 + (size_t)n * MM + mq * 16);
#pragma unroll
  for (int j = 0; j < 4; j++) {
    const float4 mv = m0p[j];
    float4 o;
    o.x = mv.x * (1.f - er[j * 4 + 0]) + ad[j * 4 + 0];
    o.y = mv.y * (1.f - er[j * 4 + 1]) + ad[j * 4 + 1];
    o.z = mv.z * (1.f - er[j * 4 + 2]) + ad[j * 4 + 2];
    o.w = mv.w * (1.f - er[j * 4 + 3]) + ad[j * 4 + 3];
    m1p[j] = o;
  }
}

// ---------------------------------------------------------------------------
// K6: fused wpow + GEMM for the 4 read heads. grid (512 n-chunks of 128,
// 2 r-pairs), block 256. Per 64-n subtile: stage m1 tile + g*rinv*E (halo)
// in LDS; per r: compute w_pow into w_sh (shfl shift + predicated halo),
// then b128 FMA loop. W is never materialized. GS_r -> scalar atomics at
// GSp[(1+r)*1024].
// ---------------------------------------------------------------------------
__global__ __launch_bounds__(256) void wpow_gemm_kernel(
    const float* __restrict__ E, const float* __restrict__ wr,
    const float* __restrict__ RSp, const float* __restrict__ g,
    const float* __restrict__ gamma_, const float* __restrict__ s,
    const float* __restrict__ m1, float* __restrict__ part,
    float* __restrict__ GSp)
{
  __shared__ float m1_sh[64][68];
  __shared__ float ge_sh[64][66];   // [b][0]=n-1 halo, [1+l]=nb+l, [65]=nb+64 halo
  __shared__ float w_sh[64][68];
  __shared__ float rinv_sh[64], omg_sh[64], gm_sh[64];
  __shared__ float s0_sh[64], s1_sh[64], s2_sh[64];
  __shared__ float wsum[4][2];

  const int t = threadIdx.x;
  const int w = t >> 6, lane = t & 63;
  const int mq = t & 15, bq = t >> 4;
  const int n0 = blockIdx.x * 128;
  const int r0 = blockIdx.y * 2;

  if (t < 64) {
    float rs = 0.f;
#pragma unroll
    for (int j = 0; j < 16; j++) rs += RSp[t * 256 + j * 16];
    const float gb = g[t];
    rinv_sh[t] = gb / rs;            // fold g: ge = (g/RS)*E
    omg_sh[t]  = 1.f - gb;
    gm_sh[t]   = gamma_[t];
    s0_sh[t] = s[t * 3 + 0];
    s1_sh[t] = s[t * 3 + 1];
    s2_sh[t] = s[t * 3 + 2];
  }
  __syncthreads();

  float4 acc[2][4];
#pragma unroll
  for (int rr = 0; rr < 2; rr++)
#pragma unroll
    for (int j = 0; j < 4; j++) acc[rr][j] = make_float4(0.f, 0.f, 0.f, 0.f);
  float gs_acc[2] = {0.f, 0.f};

  for (int sub = 0; sub < 2; ++sub) {
    const int nb = n0 + sub * 64;
    // stage m1 subtile rows nb..nb+63
#pragma unroll
    for (int rep = 0; rep < 4; rep++) {
      const int nl2 = rep * 16 + bq;
      *((float4*)&m1_sh[nl2][mq * 4]) =
          ((const float4*)(m1 + (size_t)(nb + nl2) * MM))[mq];
    }
    // stage ge = grinv*E with +-1 halo; wave w owns b in [w*16, w*16+16)
#pragma unroll 4
    for (int i = 0; i < 16; i++) {
      const int b = w * 16 + i;
      const float gr = rinv_sh[b];
      ge_sh[b][1 + lane] = gr * E[(size_t)b * NN + nb + lane];
      if (lane == 0)
        ge_sh[b][0] = (nb > 0) ? gr * E[(size_t)b * NN + nb - 1] : 0.f;
      if (lane == 63)
        ge_sh[b][65] = (nb + 64 < NN) ? gr * E[(size_t)b * NN + nb + 64] : 0.f;
    }
    __syncthreads();
#pragma unroll
    for (int rr = 0; rr < 2; ++rr) {
      const float* wrr = wr + (size_t)(r0 + rr) * BB * NN;
      // compute w_pow tile into w_sh
#pragma unroll 4
      for (int i = 0; i < 16; i++) {
        const int b = w * 16 + i;
        const float omg = omg_sh[b];
        const float* wb = wrr + (size_t)b * NN;
        const float wgc = ge_sh[b][1 + lane] + omg * wb[nb + lane];
        float wgm = __shfl_up(wgc, 1, 64);
        float wgp = __shfl_down(wgc, 1, 64);
        if (lane == 0)
          wgm = (nb > 0) ? (ge_sh[b][0] + omg * wb[nb - 1]) : 0.f;
        if (lane == 63)
          wgp = (nb + 64 < NN) ? (ge_sh[b][65] + omg * wb[nb + 64]) : 0.f;
        const float wt = s0_sh[b] * wgm + s1_sh[b] * wgc + s2_sh[b] * wgp;
        const float wp = fastPow(wt, gm_sh[b]);
        w_sh[b][lane] = wp;
        gs_acc[rr] += wp;
      }
      __syncthreads();
      // b128 FMA loop
#pragma unroll 2
      for (int c4 = 0; c4 < 16; c4++) {
        const int nn = c4 * 4;
        const float4 mv0 = *((const float4*)&m1_sh[nn + 0][mq * 4]);
        const float4 mv1 = *((const float4*)&m1_sh[nn + 1][mq * 4]);
        const float4 mv2 = *((const float4*)&m1_sh[nn + 2][mq * 4]);
        const float4 mv3 = *((const float4*)&m1_sh[nn + 3][mq * 4]);
#pragma unroll
        for (int j = 0; j < 4; j++) {
          const float4 wj = *((const float4*)&w_sh[bq * 4 + j][nn]);
          float4& a = acc[rr][j];
          a.x += wj.x * mv0.x + wj.y * mv1.x + wj.z * mv2.x + wj.w * mv3.x;
          a.y += wj.x * mv0.y + wj.y * mv1.y + wj.z * mv2.y + wj.w * mv3.y;
          a.z += wj.x * mv0.z + wj.y * mv1.z + wj.z * mv2.z + wj.w * mv3.z;
          a.w += wj.x * mv0.w + wj.y * mv1.w + wj.z * mv2.w + wj.w * mv3.w;
        }
      }
      __syncthreads();  // before next rr/sub overwrites w_sh / ge_sh / m1_sh
    }
  }
  // part slab: [bid.x][r][b][m], slab stride 4*4096
#pragma unroll
  for (int rr = 0; rr < 2; rr++)
#pragma unroll
    for (int j = 0; j < 4; j++)
      *((float4*)&part[((size_t)blockIdx.x * 4 + r0 + rr) * 4096 +
                       (bq * 4 + j) * 64 + mq * 4]) = acc[rr][j];
  // GS_r scalar accumulation
#pragma unroll
  for (int rr = 0; rr < 2; rr++) {
    const float v = waveReduceSum(gs_acc[rr]);
    if (lane == 0) wsum[w][rr] = v;
  }
  __syncthreads();
  if (t < 2)
    atomicAdd(&GSp[(1 + r0 + t) * 1024],
              wsum[0][t] + wsum[1][t] + wsum[2][t] + wsum[3][t]);
}

// ---------------------------------------------------------------------------
// K7: reduce 512 partial slabs + normalize by GS_r. grid 256, block 1024.
// GS_r is the scalar at GSp[(1+r)*1024].
// ---------------------------------------------------------------------------
__global__ __launch_bounds__(1024) void reduce_norm_kernel(
    const float* __restrict__ part, const float* __restrict__ GSp,
    float* __restrict__ out)
{
  const int t = threadIdx.x;
  const int ln = t & 63, wv = t >> 6;       // wv in [0,16)
  const int off = blockIdx.x * 64 + ln;     // (r*4096 + b*64 + m)
  const int r = blockIdx.x >> 6;            // 64 outputs per block -> single r
  float sm = 0.f;
#pragma unroll 8
  for (int k = wv; k < 512; k += 16) sm += part[(size_t)k * 16384 + off];
  __shared__ float red[16][64];
  red[wv][ln] = sm;
  __syncthreads();
  if (t < 64) {
    const float gv = GSp[(1 + r) * 1024];
    float sum = 0.f;
#pragma unroll
    for (int j = 0; j < 16; j++) sum += red[j][t];
    const int off2 = blockIdx.x * 64 + t;
    const int b = (off2 >> 6) & 63, m = off2 & 63;
    out[b * 256 + r * 64 + m] = sum / (gv + 1e-5f);
  }
}

// ---------------------------------------------------------------------------
extern "C" void kernel_launch(void* const* d_in, const int* in_sizes, int n_in,
                              void* d_out, int out_size, void* d_ws, size_t ws_size,
                              hipStream_t stream) {
  (void)in_sizes; (void)n_in; (void)out_size; (void)ws_size;
  const float* h_t    = (const float*)d_in[0];
  const float* ww     = (const float*)d_in[1];
  const float* wr     = (const float*)d_in[2];
  const float* memory = (const float*)d_in[3];
  const float* key_w  = (const float*)d_in[4];
  const float* key_b  = (const float*)d_in[5];
  const float* beta_w = (const float*)d_in[6];
  const float* beta_b = (const float*)d_in[7];
  const float* gate_w = (const float*)d_in[8];
  const float* gate_b = (const float*)d_in[9];
  const float* shift_w = (const float*)d_in[10];
  const float* shift_b = (const float*)d_in[11];
  const float* gamma_w = (const float*)d_in[12];
  const float* gamma_b = (const float*)d_in[13];
  const float* erase_w = (const float*)d_in[14];
  const float* erase_b = (const float*)d_in[15];
  const float* add_w   = (const float*)d_in[16];
  const float* add_b   = (const float*)d_in[17];
  const int*   bank    = (const int*)d_in[18];

  float* ws = (float*)d_ws;
  // slab layout (floats):
  //   [0, 4.2M)    E0 (content0 -> wpow<1>);   part reuses [0, 8.4M) later
  //   [4.2M, 8.4M) W0 (wpow<1> -> apply)
  //   [8.4M,12.6M) m1 (apply -> content1, wpow_gemm)
  //   [12.6M,16.8M) E1 (content1 -> wpow_gemm)
  float* E0    = ws;
  float* part  = ws;                     // 8.4M floats, live after apply
  float* W0    = ws + 4194304;
  float* m1    = ws + 8388608;
  float* E1    = ws + 12582912;
  float* smallb  = ws + 16777216;
  float* kn       = smallb + 16384;      // 4096
  float* e_v      = smallb + 20480;      // 4096
  float* a_v      = smallb + 24576;      // 4096
  float* betaB    = smallb + 28672;      // 64
  float* g        = smallb + 28736;      // 64
  float* gam      = smallb + 28800;      // 64
  float* s        = smallb + 28864;      // 256 (192 used)
  float* RS0p     = smallb + 29120;      // 16384
  float* RS1p     = smallb + 45504;      // 16384
  float* GSp      = smallb + 61888;      // 5120 (slot0: write head per-b; 1..4: scalar GS_r)
  float* prep_part = smallb + 67008;     // 49152

  prep1_kernel<<<dim3(12, 64), 256, 0, stream>>>(h_t, key_w, erase_w, add_w,
                                                 prep_part, RS0p, RS1p, GSp);
  prep2_kernel<<<64, 256, 0, stream>>>(h_t, prep_part, key_b,
                                       beta_w, beta_b, gate_w, gate_b,
                                       shift_w, shift_b, gamma_w, gamma_b,
                                       erase_b, add_b,
                                       kn, e_v, a_v, g, gam, s, betaB);
  content_kernel<<<1024, 256, 0, stream>>>(memory, bank, kn, betaB, E0, RS0p);
  wpow_all_kernel<1><<<dim3(64, 64), 256, 0, stream>>>(E0, ww, RS0p, g, gam, s,
                                                       W0, GSp, 0);
  apply_write_kernel<<<1024, 256, 0, stream>>>(W0, GSp, e_v, a_v, memory, bank, m1);
  content_kernel<<<1024, 256, 0, stream>>>(m1, nullptr, kn, betaB, E1, RS1p);
  wpow_gemm_kernel<<<dim3(512, 2), 256, 0, stream>>>(E1, wr, RS1p, g, gam, s,
                                                     m1, part, GSp);
  reduce_norm_kernel<<<256, 1024, 0, stream>>>(part, GSp, (float*)d_out);
}

// Round 5
// 168.387 us; speedup vs baseline: 1.8284x; 1.8284x over previous
//
#include <hip/hip_runtime.h>

#define NN 65536
#define BB 64
#define HH 1024
#define MM 64
#define RR 4

__device__ __forceinline__ float waveReduceSum(float v) {
#pragma unroll
  for (int off = 32; off > 0; off >>= 1) v += __shfl_xor(v, off, 64);
  return v;
}

__device__ __forceinline__ float fastPow(float wt, float p) {
  return __expf(p * __logf(wt));
}

// ---------------------------------------------------------------------------
// K1a: partial dots for the three 1024x64 GEMMs. grid (12, 64), block 256.
// ---------------------------------------------------------------------------
__global__ __launch_bounds__(256) void prep1_kernel(
    const float* __restrict__ h_t,
    const float* __restrict__ key_w, const float* __restrict__ erase_w,
    const float* __restrict__ add_w,
    float* __restrict__ prep_part,
    float* __restrict__ RS0p, float* __restrict__ RS1p, float* __restrict__ GSp)
{
  const int b = blockIdx.y;
  const int mat = blockIdx.x >> 2, chunk = blockIdx.x & 3;
  const int t = threadIdx.x;
  if (mat == 0 && chunk == 0) { RS0p[b * 256 + t] = 0.f; RS1p[b * 256 + t] = 0.f; }
  if (mat == 0 && chunk == 1 && b < 20) GSp[b * 256 + t] = 0.f;

  const float* Wm = (mat == 0) ? key_w : ((mat == 1) ? erase_w : add_w);
  const int c = t & 63, q = t >> 6;
  const int h0 = chunk * 256 + q * 64;
  float d = 0.f;
#pragma unroll 8
  for (int i = 0; i < 64; i++)
    d += h_t[b * HH + h0 + i] * Wm[(h0 + i) * 64 + c];
  __shared__ float red[64][5];
  red[c][q] = d;
  __syncthreads();
  if (t < 64)
    prep_part[((b * 3 + mat) * 4 + chunk) * 64 + t] =
        red[t][0] + red[t][1] + red[t][2] + red[t][3];
}

// ---------------------------------------------------------------------------
// K1b: reduce partials + activations + small dots + kn. grid 64, block 256.
// ---------------------------------------------------------------------------
__global__ __launch_bounds__(256) void prep2_kernel(
    const float* __restrict__ h_t, const float* __restrict__ prep_part,
    const float* __restrict__ key_b,
    const float* __restrict__ beta_w, const float* __restrict__ beta_b,
    const float* __restrict__ gate_w, const float* __restrict__ gate_b,
    const float* __restrict__ shift_w, const float* __restrict__ shift_b,
    const float* __restrict__ gamma_w, const float* __restrict__ gamma_b,
    const float* __restrict__ erase_b, const float* __restrict__ add_b,
    float* __restrict__ kn, float* __restrict__ e_v, float* __restrict__ a_v,
    float* __restrict__ g, float* __restrict__ gamma_,
    float* __restrict__ s, float* __restrict__ betaGlob)
{
  const int b = blockIdx.x;
  const int t = threadIdx.x;
  __shared__ float k_sh[64];
  if (t < 192) {
    const int mat = t >> 6, c = t & 63;
    const float* pp = prep_part + ((b * 3 + mat) * 4) * 64 + c;
    const float v = pp[0] + pp[64] + pp[128] + pp[192];
    if (mat == 0) k_sh[c] = fminf(fmaxf(v + key_b[c], 0.f), 1.f);
    else if (mat == 1) e_v[b * 64 + c] = fminf(fmaxf(v + erase_b[c], 0.f), 1.f);
    else a_v[b * 64 + c] = fminf(fmaxf(v + add_b[c], 0.f), 1.f);
  } else {
    const int lane = t - 192;
    float o0 = 0.f, o1 = 0.f, o2 = 0.f, o3 = 0.f, o4 = 0.f, o5 = 0.f;
#pragma unroll 4
    for (int k = 0; k < 16; k++) {
      const int hh = lane + k * 64;
      const float hv = h_t[b * HH + hh];
      o0 += hv * beta_w[hh];
      o1 += hv * gate_w[hh];
      o2 += hv * gamma_w[hh];
      o3 += hv * shift_w[hh * 3 + 0];
      o4 += hv * shift_w[hh * 3 + 1];
      o5 += hv * shift_w[hh * 3 + 2];
    }
    o0 = waveReduceSum(o0); o1 = waveReduceSum(o1); o2 = waveReduceSum(o2);
    o3 = waveReduceSum(o3); o4 = waveReduceSum(o4); o5 = waveReduceSum(o5);
    if (lane == 0) {
      betaGlob[b] = fmaxf(o0 + beta_b[0], 0.f);
      g[b]        = fminf(fmaxf(o1 + gate_b[0], 0.f), 1.f);
      gamma_[b]   = 1.0f + fmaxf(o2 + gamma_b[0], 0.f);
      const float l0 = o3 + shift_b[0], l1 = o4 + shift_b[1], l2 = o5 + shift_b[2];
      const float mx = fmaxf(l0, fmaxf(l1, l2));
      const float e0 = __expf(l0 - mx), e1 = __expf(l1 - mx), e2 = __expf(l2 - mx);
      const float inv = 1.f / (e0 + e1 + e2);
      s[b * 3 + 0] = e0 * inv; s[b * 3 + 1] = e1 * inv; s[b * 3 + 2] = e2 * inv;
    }
  }
  __syncthreads();
  if (t < 64) {
    float ss = 0.f;
    for (int j = 0; j < 64; j++) ss += k_sh[j] * k_sh[j];
    kn[b * 64 + t] = k_sh[t] / (sqrtf(ss) + 1e-8f);
  }
}

// ---------------------------------------------------------------------------
// K2 / K5: content addressing. grid 1024 (n-chunks of 64), block 256.
// Memory row resident in VGPRs; kn/beta via wave-uniform scalar loads.
// ---------------------------------------------------------------------------
__global__ __launch_bounds__(256, 4) void content_kernel(
    const float* __restrict__ mem, const int* __restrict__ bank,
    const float* __restrict__ kn, const float* __restrict__ beta,
    float* __restrict__ E, float* __restrict__ RSp)
{
  const float* Mrow = mem + (bank ? ((size_t)(*bank) * (size_t)NN * MM) : (size_t)0);
  const int t = threadIdx.x;
  const int lane = t & 63;
  const int n = blockIdx.x * 64 + lane;
  const int bq = t >> 6;  // wave id -> b group

  float4 row[16];
  const float4* rp = (const float4*)(Mrow + (size_t)n * MM);
#pragma unroll
  for (int q = 0; q < 16; q++) row[q] = rp[q];
  float s0 = 0.f, s1 = 0.f, s2 = 0.f, s3 = 0.f;
#pragma unroll
  for (int q = 0; q < 16; q++) {
    s0 += row[q].x * row[q].x; s1 += row[q].y * row[q].y;
    s2 += row[q].z * row[q].z; s3 += row[q].w * row[q].w;
  }
  const float rinv = 1.0f / (sqrtf((s0 + s1) + (s2 + s3)) + 1e-8f);

#pragma unroll 2
  for (int i = 0; i < 16; i++) {
    const int rb = __builtin_amdgcn_readfirstlane(bq * 16 + i);
    const float4* kp = (const float4*)(kn + rb * 64);
    float d0 = 0.f, d1 = 0.f, d2 = 0.f, d3 = 0.f;
#pragma unroll
    for (int q = 0; q < 16; q++) {
      const float4 kq = kp[q];
      d0 += kq.x * row[q].x; d1 += kq.y * row[q].y;
      d2 += kq.z * row[q].z; d3 += kq.w * row[q].w;
    }
    const float e = __expf(beta[rb] * ((d0 + d1) + (d2 + d3)) * rinv);
    E[(size_t)rb * NN + n] = e;
    const float r = waveReduceSum(e);
    if (lane == 0)
      atomicAdd(&RSp[rb * 256 + (blockIdx.x & 15) * 16], r);
  }
}

// ---------------------------------------------------------------------------
// K3: vectorized streaming w_pow (write head, NR=1). grid (64, 64), block 256.
// ---------------------------------------------------------------------------
template <int NR>
__global__ __launch_bounds__(256) void wpow_all_kernel(
    const float* __restrict__ E, const float* __restrict__ wprev,
    const float* __restrict__ RSp, const float* __restrict__ g,
    const float* __restrict__ gamma_, const float* __restrict__ s,
    float* __restrict__ Wout, float* __restrict__ GSp, int slot0)
{
  const int b = blockIdx.y;
  const float gb = g[b], gmb = gamma_[b];
  const float s0 = s[b * 3], s1 = s[b * 3 + 1], s2 = s[b * 3 + 2];
  float rs = 0.f;
#pragma unroll
  for (int j = 0; j < 16; j++) rs += RSp[b * 256 + j * 16];
  const float grinv = gb / rs;
  const float omg = 1.f - gb;

  const int t = threadIdx.x, lane = t & 63, w = t >> 6;
  const int n4 = blockIdx.x * 1024 + 4 * t;

  const float* Eb = E + (size_t)b * NN;
  const float4 ev = *((const float4*)(Eb + n4));
  const float gex = grinv * ev.x, gey = grinv * ev.y;
  const float gez = grinv * ev.z, gew = grinv * ev.w;
  float geL = 0.f, geR = 0.f;
  if (lane == 0 && n4 > 0) geL = grinv * Eb[n4 - 1];
  if (lane == 63 && n4 + 4 < NN) geR = grinv * Eb[n4 + 4];

  float gs_local[NR];
#pragma unroll
  for (int j = 0; j < NR; j++) gs_local[j] = 0.f;

#pragma unroll
  for (int j = 0; j < NR; j++) {
    const float* wb = wprev + ((size_t)j * BB + b) * NN;
    const float4 wv = *((const float4*)(wb + n4));
    float4 wgc;
    wgc.x = gex + omg * wv.x;
    wgc.y = gey + omg * wv.y;
    wgc.z = gez + omg * wv.z;
    wgc.w = gew + omg * wv.w;
    float up = __shfl_up(wgc.w, 1, 64);
    float dn = __shfl_down(wgc.x, 1, 64);
    if (lane == 0)  up = (n4 > 0)       ? (geL + omg * wb[n4 - 1]) : 0.f;
    if (lane == 63) dn = (n4 + 4 < NN)  ? (geR + omg * wb[n4 + 4]) : 0.f;
    float4 wt;
    wt.x = s0 * up    + s1 * wgc.x + s2 * wgc.y;
    wt.y = s0 * wgc.x + s1 * wgc.y + s2 * wgc.z;
    wt.z = s0 * wgc.y + s1 * wgc.z + s2 * wgc.w;
    wt.w = s0 * wgc.z + s1 * wgc.w + s2 * dn;
    float4 wp;
    wp.x = fastPow(wt.x, gmb); wp.y = fastPow(wt.y, gmb);
    wp.z = fastPow(wt.z, gmb); wp.w = fastPow(wt.w, gmb);
    *((float4*)(Wout + ((size_t)j * BB + b) * NN + n4)) = wp;
    gs_local[j] += wp.x + wp.y + wp.z + wp.w;
  }

  __shared__ float wsum[4][NR];
#pragma unroll
  for (int j = 0; j < NR; j++) {
    const float v = waveReduceSum(gs_local[j]);
    if (lane == 0) wsum[w][j] = v;
  }
  __syncthreads();
  if (t < NR)
    atomicAdd(&GSp[(slot0 + t) * 1024 + b * 16],
              wsum[0][t] + wsum[1][t] + wsum[2][t] + wsum[3][t]);
}

// ---------------------------------------------------------------------------
// K4: apply write head. grid 1024 (64-n), block 256.
// ---------------------------------------------------------------------------
__global__ __launch_bounds__(256) void apply_write_kernel(
    const float* __restrict__ W0, const float* __restrict__ GSp,
    const float* __restrict__ e_v, const float* __restrict__ a_v,
    const float* __restrict__ memory, const int* __restrict__ bank,
    float* __restrict__ m1)
{
  __shared__ float cw[64 * 68];
  __shared__ float e_sh[4096];
  __shared__ float a_sh[4096];
  const int t = threadIdx.x;
  const int n0 = blockIdx.x * 64;
  float gs = 0.f;
#pragma unroll
  for (int j = 0; j < 64; j++) gs += GSp[j * 16];
  const float invGS = 1.0f / (gs + 1e-5f);
#pragma unroll
  for (int q = 0; q < 4; q++) {
    ((float4*)e_sh)[t + 256 * q] = ((const float4*)e_v)[t + 256 * q];
    ((float4*)a_sh)[t + 256 * q] = ((const float4*)a_v)[t + 256 * q];
  }
#pragma unroll
  for (int rep = 0; rep < 4; rep++) {
    const int idx = rep * 256 + t;
    const int b = idx >> 4, nc = idx & 15;
    float4 v = *((const float4*)(W0 + (size_t)b * NN + n0 + nc * 4));
    v.x *= invGS; v.y *= invGS; v.z *= invGS; v.w *= invGS;
    *((float4*)&cw[b * 68 + nc * 4]) = v;
  }
  __syncthreads();
  const int nl = t >> 2, mq = t & 3;
  const int n = n0 + nl;
  float er[16], ad[16];
#pragma unroll
  for (int j = 0; j < 16; j++) { er[j] = 0.f; ad[j] = 0.f; }
  for (int b = 0; b < 64; b++) {
    const float c = cw[b * 68 + nl];
#pragma unroll
    for (int j = 0; j < 4; j++) {
      const float4 ev = *((const float4*)&e_sh[b * 64 + mq * 16 + j * 4]);
      const float4 av = *((const float4*)&a_sh[b * 64 + mq * 16 + j * 4]);
      er[j * 4 + 0] += c * ev.x; er[j * 4 + 1] += c * ev.y;
      er[j * 4 + 2] += c * ev.z; er[j * 4 + 3] += c * ev.w;
      ad[j * 4 + 0] += c * av.x; ad[j * 4 + 1] += c * av.y;
      ad[j * 4 + 2] += c * av.z; ad[j * 4 + 3] += c * av.w;
    }
  }
  const float* M0 = memory + (size_t)(*bank) * (size_t)NN * MM;
  const float4* m0p = (const float4*)(M0 + (size_t)n * MM + mq * 16);
  float4* m1p = (float4*)(m1 + (size_t)n * MM + mq * 16);
#pragma unroll
  for (int j = 0; j < 4; j++) {
    const float4 mv = m0p[j];
    float4 o;
    o.x = mv.x * (1.f - er[j * 4 + 0]) + ad[j * 4 + 0];
    o.y = mv.y * (1.f - er[j * 4 + 1]) + ad[j * 4 + 1];
    o.z = mv.z * (1.f - er[j * 4 + 2]) + ad[j * 4 + 2];
    o.w = mv.w * (1.f - er[j * 4 + 3]) + ad[j * 4 + 3];
    m1p[j] = o;
  }
}

// ---------------------------------------------------------------------------
// K6: fused wpow + GEMM, v2 — all phases flat. grid (512, 2), block 256.
// Per 64-n subtile: flat-stage m1, ge=(g/RS)*E, and per r the raw wr tile
// into LDS (float4 reps; halos via 128 scalar loads into tiny arrays).
// w_pow computed from LDS (thread = (row, 4n), reads 6 contiguous values,
// no shfl, no divergence), written back in place. Then the b128 FMA loop.
// ---------------------------------------------------------------------------
__global__ __launch_bounds__(256) void wpow_gemm_kernel(
    const float* __restrict__ E, const float* __restrict__ wr,
    const float* __restrict__ RSp, const float* __restrict__ g,
    const float* __restrict__ gamma_, const float* __restrict__ s,
    const float* __restrict__ m1, float* __restrict__ part,
    float* __restrict__ GSp)
{
  __shared__ float m1_sh[64][68];
  __shared__ float ge_sh[64][68];
  __shared__ float w_sh[64][68];   // wr tile, overwritten in place by wp
  __shared__ float geL[64], geR[64], wvL[64], wvR[64];
  __shared__ float rinv_sh[64], omg_sh[64], gm_sh[64];
  __shared__ float s0_sh[64], s1_sh[64], s2_sh[64];
  __shared__ float wsum[4][2];

  const int t = threadIdx.x;
  const int w = t >> 6, lane = t & 63;
  const int mq = t & 15, bq = t >> 4;   // bq: FMA b-group AND staging row-in-rep
  const int n0 = blockIdx.x * 128;
  const int r0 = blockIdx.y * 2;

  if (t < 64) {
    float rs = 0.f;
#pragma unroll
    for (int j = 0; j < 16; j++) rs += RSp[t * 256 + j * 16];
    const float gb = g[t];
    rinv_sh[t] = gb / rs;            // fold g: ge = (g/RS)*E
    omg_sh[t]  = 1.f - gb;
    gm_sh[t]   = gamma_[t];
    s0_sh[t] = s[t * 3 + 0];
    s1_sh[t] = s[t * 3 + 1];
    s2_sh[t] = s[t * 3 + 2];
  }
  __syncthreads();

  float4 acc[2][4];
#pragma unroll
  for (int rr = 0; rr < 2; rr++)
#pragma unroll
    for (int j = 0; j < 4; j++) acc[rr][j] = make_float4(0.f, 0.f, 0.f, 0.f);
  float gs_acc[2] = {0.f, 0.f};

  for (int sub = 0; sub < 2; ++sub) {
    const int nb = n0 + sub * 64;
    // flat stage: m1 tile + ge tile (+ ge halos)
#pragma unroll
    for (int rep = 0; rep < 4; rep++) {
      const int row = rep * 16 + bq;
      *((float4*)&m1_sh[row][mq * 4]) =
          ((const float4*)(m1 + (size_t)(nb + row) * MM))[mq];
      const float gr = rinv_sh[row];
      const float4 e4 = *((const float4*)(E + (size_t)row * NN + nb + mq * 4));
      float4 ge4;
      ge4.x = gr * e4.x; ge4.y = gr * e4.y; ge4.z = gr * e4.z; ge4.w = gr * e4.w;
      *((float4*)&ge_sh[row][mq * 4]) = ge4;
    }
    if (t < 64)
      geL[t] = (nb > 0) ? rinv_sh[t] * E[(size_t)t * NN + nb - 1] : 0.f;
    else if (t < 128)
      geR[t - 64] = (nb + 64 < NN)
                        ? rinv_sh[t - 64] * E[(size_t)(t - 64) * NN + nb + 64] : 0.f;

    for (int rr = 0; rr < 2; ++rr) {
      const float* wrr = wr + (size_t)(r0 + rr) * BB * NN;
      // flat stage: wr tile + halos
#pragma unroll
      for (int rep = 0; rep < 4; rep++) {
        const int row = rep * 16 + bq;
        *((float4*)&w_sh[row][mq * 4]) =
            *((const float4*)(wrr + (size_t)row * NN + nb + mq * 4));
      }
      if (t < 64)
        wvL[t] = (nb > 0) ? wrr[(size_t)t * NN + nb - 1] : 0.f;
      else if (t < 128)
        wvR[t - 64] = (nb + 64 < NN) ? wrr[(size_t)(t - 64) * NN + nb + 64] : 0.f;
      __syncthreads();  // B1: staged tiles visible

      // compute wp in registers from LDS (flat, no shfl)
      float4 wp[4];
      float lsum = 0.f;
#pragma unroll
      for (int rep = 0; rep < 4; rep++) {
        const int b = rep * 16 + bq;
        const int n4 = mq * 4;
        const float omg = omg_sh[b];
        const float c0 = s0_sh[b], c1 = s1_sh[b], c2 = s2_sh[b];
        const float gm = gm_sh[b];
        const float4 ge4 = *((const float4*)&ge_sh[b][n4]);
        const float4 wv4 = *((const float4*)&w_sh[b][n4]);
        const float wg0 = ge4.x + omg * wv4.x;
        const float wg1 = ge4.y + omg * wv4.y;
        const float wg2 = ge4.z + omg * wv4.z;
        const float wg3 = ge4.w + omg * wv4.w;
        const float wgm = (n4 == 0)
            ? (geL[b] + omg * wvL[b])
            : (ge_sh[b][n4 - 1] + omg * w_sh[b][n4 - 1]);
        const float wgp = (n4 == 60)
            ? (geR[b] + omg * wvR[b])
            : (ge_sh[b][n4 + 4] + omg * w_sh[b][n4 + 4]);
        wp[rep].x = fastPow(c0 * wgm + c1 * wg0 + c2 * wg1, gm);
        wp[rep].y = fastPow(c0 * wg0 + c1 * wg1 + c2 * wg2, gm);
        wp[rep].z = fastPow(c0 * wg1 + c1 * wg2 + c2 * wg3, gm);
        wp[rep].w = fastPow(c0 * wg2 + c1 * wg3 + c2 * wgp, gm);
        lsum += (wp[rep].x + wp[rep].y) + (wp[rep].z + wp[rep].w);
      }
      gs_acc[rr] += lsum;
      __syncthreads();  // B2: all reads of raw wr done before overwrite

#pragma unroll
      for (int rep = 0; rep < 4; rep++)
        *((float4*)&w_sh[rep * 16 + bq][mq * 4]) = wp[rep];
      __syncthreads();  // B3: wp tile visible

      // b128 FMA loop
#pragma unroll 2
      for (int c4 = 0; c4 < 16; c4++) {
        const int nn = c4 * 4;
        const float4 mv0 = *((const float4*)&m1_sh[nn + 0][mq * 4]);
        const float4 mv1 = *((const float4*)&m1_sh[nn + 1][mq * 4]);
        const float4 mv2 = *((const float4*)&m1_sh[nn + 2][mq * 4]);
        const float4 mv3 = *((const float4*)&m1_sh[nn + 3][mq * 4]);
#pragma unroll
        for (int j = 0; j < 4; j++) {
          const float4 wj = *((const float4*)&w_sh[bq * 4 + j][nn]);
          float4& a = acc[rr][j];
          a.x += wj.x * mv0.x + wj.y * mv1.x + wj.z * mv2.x + wj.w * mv3.x;
          a.y += wj.x * mv0.y + wj.y * mv1.y + wj.z * mv2.y + wj.w * mv3.y;
          a.z += wj.x * mv0.z + wj.y * mv1.z + wj.z * mv2.z + wj.w * mv3.z;
          a.w += wj.x * mv0.w + wj.y * mv1.w + wj.z * mv2.w + wj.w * mv3.w;
        }
      }
      __syncthreads();  // B4: FMA reads done before next stage overwrites
    }
  }
  // part slab: [bid.x][r][b][m], slab stride 4*4096
#pragma unroll
  for (int rr = 0; rr < 2; rr++)
#pragma unroll
    for (int j = 0; j < 4; j++)
      *((float4*)&part[((size_t)blockIdx.x * 4 + r0 + rr) * 4096 +
                       (bq * 4 + j) * 64 + mq * 4]) = acc[rr][j];
  // GS_r scalar accumulation
#pragma unroll
  for (int rr = 0; rr < 2; rr++) {
    const float v = waveReduceSum(gs_acc[rr]);
    if (lane == 0) wsum[w][rr] = v;
  }
  __syncthreads();
  if (t < 2)
    atomicAdd(&GSp[(1 + r0 + t) * 1024],
              wsum[0][t] + wsum[1][t] + wsum[2][t] + wsum[3][t]);
}

// ---------------------------------------------------------------------------
// K7: reduce 512 partial slabs + normalize by GS_r. grid 256, block 1024.
// ---------------------------------------------------------------------------
__global__ __launch_bounds__(1024) void reduce_norm_kernel(
    const float* __restrict__ part, const float* __restrict__ GSp,
    float* __restrict__ out)
{
  const int t = threadIdx.x;
  const int ln = t & 63, wv = t >> 6;       // wv in [0,16)
  const int off = blockIdx.x * 64 + ln;     // (r*4096 + b*64 + m)
  const int r = blockIdx.x >> 6;            // 64 outputs per block -> single r
  float sm = 0.f;
#pragma unroll 8
  for (int k = wv; k < 512; k += 16) sm += part[(size_t)k * 16384 + off];
  __shared__ float red[16][64];
  red[wv][ln] = sm;
  __syncthreads();
  if (t < 64) {
    const float gv = GSp[(1 + r) * 1024];
    float sum = 0.f;
#pragma unroll
    for (int j = 0; j < 16; j++) sum += red[j][t];
    const int off2 = blockIdx.x * 64 + t;
    const int b = (off2 >> 6) & 63, m = off2 & 63;
    out[b * 256 + r * 64 + m] = sum / (gv + 1e-5f);
  }
}

// ---------------------------------------------------------------------------
extern "C" void kernel_launch(void* const* d_in, const int* in_sizes, int n_in,
                              void* d_out, int out_size, void* d_ws, size_t ws_size,
                              hipStream_t stream) {
  (void)in_sizes; (void)n_in; (void)out_size; (void)ws_size;
  const float* h_t    = (const float*)d_in[0];
  const float* ww     = (const float*)d_in[1];
  const float* wr     = (const float*)d_in[2];
  const float* memory = (const float*)d_in[3];
  const float* key_w  = (const float*)d_in[4];
  const float* key_b  = (const float*)d_in[5];
  const float* beta_w = (const float*)d_in[6];
  const float* beta_b = (const float*)d_in[7];
  const float* gate_w = (const float*)d_in[8];
  const float* gate_b = (const float*)d_in[9];
  const float* shift_w = (const float*)d_in[10];
  const float* shift_b = (const float*)d_in[11];
  const float* gamma_w = (const float*)d_in[12];
  const float* gamma_b = (const float*)d_in[13];
  const float* erase_w = (const float*)d_in[14];
  const float* erase_b = (const float*)d_in[15];
  const float* add_w   = (const float*)d_in[16];
  const float* add_b   = (const float*)d_in[17];
  const int*   bank    = (const int*)d_in[18];

  float* ws = (float*)d_ws;
  // slab layout (floats):
  //   [0, 4.2M)    E0 (content0 -> wpow<1>);   part reuses [0, 8.4M) later
  //   [4.2M, 8.4M) W0 (wpow<1> -> apply)
  //   [8.4M,12.6M) m1 (apply -> content1, wpow_gemm)
  //   [12.6M,16.8M) E1 (content1 -> wpow_gemm)
  float* E0    = ws;
  float* part  = ws;                     // 8.4M floats, live after apply
  float* W0    = ws + 4194304;
  float* m1    = ws + 8388608;
  float* E1    = ws + 12582912;
  float* smallb  = ws + 16777216;
  float* kn       = smallb + 16384;      // 4096
  float* e_v      = smallb + 20480;      // 4096
  float* a_v      = smallb + 24576;      // 4096
  float* betaB    = smallb + 28672;      // 64
  float* g        = smallb + 28736;      // 64
  float* gam      = smallb + 28800;      // 64
  float* s        = smallb + 28864;      // 256 (192 used)
  float* RS0p     = smallb + 29120;      // 16384
  float* RS1p     = smallb + 45504;      // 16384
  float* GSp      = smallb + 61888;      // 5120 (slot0: write head per-b; 1..4: scalar GS_r)
  float* prep_part = smallb + 67008;     // 49152

  prep1_kernel<<<dim3(12, 64), 256, 0, stream>>>(h_t, key_w, erase_w, add_w,
                                                 prep_part, RS0p, RS1p, GSp);
  prep2_kernel<<<64, 256, 0, stream>>>(h_t, prep_part, key_b,
                                       beta_w, beta_b, gate_w, gate_b,
                                       shift_w, shift_b, gamma_w, gamma_b,
                                       erase_b, add_b,
                                       kn, e_v, a_v, g, gam, s, betaB);
  content_kernel<<<1024, 256, 0, stream>>>(memory, bank, kn, betaB, E0, RS0p);
  wpow_all_kernel<1><<<dim3(64, 64), 256, 0, stream>>>(E0, ww, RS0p, g, gam, s,
                                                       W0, GSp, 0);
  apply_write_kernel<<<1024, 256, 0, stream>>>(W0, GSp, e_v, a_v, memory, bank, m1);
  content_kernel<<<1024, 256, 0, stream>>>(m1, nullptr, kn, betaB, E1, RS1p);
  wpow_gemm_kernel<<<dim3(512, 2), 256, 0, stream>>>(E1, wr, RS1p, g, gam, s,
                                                     m1, part, GSp);
  reduce_norm_kernel<<<256, 1024, 0, stream>>>(part, GSp, (float*)d_out);
}